// Round 4
// baseline (249.041 us; speedup 1.0000x reference)
//
#include <hip/hip_runtime.h>
#include <math.h>

// Modulated conv2d (StyleGAN2): B=8, I=O=512, H=W=64, K=3, fp32 in/out.
// R4: conv identical to R3 (bf16 MFMA implicit-GEMM, dbuf, tap-prefetch).
// Prologue rebuilt: K1={style, w2, pack_w(LDS transpose, coalesced)},
// K2={demod, pack_x}. 3 launches total.

typedef short short8 __attribute__((ext_vector_type(8)));
typedef float floatx4 __attribute__((ext_vector_type(4)));
typedef unsigned short ushort_t;

#define COUT  512

// float -> bf16 RNE
__device__ __forceinline__ ushort_t f2bf(float f) {
    union { float f; unsigned u; } v; v.f = f;
    unsigned r = v.u + 0x7fff + ((v.u >> 16) & 1);
    return (ushort_t)(r >> 16);
}

__device__ __forceinline__ void gload_lds16(const void* g, void* l) {
    __builtin_amdgcn_global_load_lds(
        (const __attribute__((address_space(1))) unsigned int*)g,
        (__attribute__((address_space(3))) unsigned int*)l, 16, 0, 0);
}

// ---------- K1: style (blocks 0..1023) + w2 (1024..2047) + pack_w (2048..2559)
// style[b][i] = (dl[b].dw[i])/sqrt(512) + db[i];  w2[o][i] = sum_tap w^2
// wpk[ck16][tap9][osub32][lane64][j8]; o=osub*16+(lane&15), i=ck*32+(lane>>4)*8+j
__global__ void k1_style_w2_packw(const float* __restrict__ dl,
                                  const float* __restrict__ dw,
                                  const float* __restrict__ db,
                                  const float* __restrict__ w,
                                  float* __restrict__ style,
                                  float* __restrict__ w2,
                                  ushort_t* __restrict__ wpk) {
    __shared__ float tile[16 * 288];
    if (blockIdx.x < 1024) {
        int gw   = (blockIdx.x * 256 + threadIdx.x) >> 6;
        int lane = threadIdx.x & 63;
        int b = gw >> 9;
        int i = gw & 511;
        const float* dlp = dl + b * 512;
        const float* dwp = dw + (size_t)i * 512;
        float acc = 0.f;
        #pragma unroll
        for (int d = 0; d < 512; d += 64) acc += dlp[d + lane] * dwp[d + lane];
        #pragma unroll
        for (int off = 32; off > 0; off >>= 1) acc += __shfl_down(acc, off, 64);
        if (lane == 0) style[b * 512 + i] = acc * 0.044194173824159216f + db[i];
    } else if (blockIdx.x < 2048) {
        int idx = (blockIdx.x - 1024) * 256 + threadIdx.x;
        const float* wp = w + (size_t)idx * 9;
        float s = 0.f;
        #pragma unroll
        for (int t = 0; t < 9; t++) s += wp[t] * wp[t];
        w2[idx] = s;
    } else {
        // pack_w: block = (ck, osub); 512 blocks
        int bid  = blockIdx.x - 2048;
        int osub = bid & 31;
        int ck   = bid >> 5;
        int tid  = threadIdx.x;
        // load 16 rows (o = osub*16+row) x 288 floats (i=ck*32..+32, taps 0..8), coalesced
        const float* src = w + ((size_t)osub * 16 * 512 + ck * 32) * 9;
        #pragma unroll
        for (int k = 0; k < 18; k++) {
            int idx = tid + k * 256;           // 0..4607
            int row = idx >> 8;                 // idx/288? no: use exact div below
            // exact: row = idx / 288, col = idx % 288
            row = idx / 288;
            int col = idx - row * 288;
            tile[row * 288 + col] = src[(size_t)row * 512 * 9 + col];
        }
        __syncthreads();
        const float cs = 0.014731391274719738f;   // 1/sqrt(4608)
        ushort_t* dst = wpk + ((size_t)(ck * 9) * 32 + osub) * 64 * 8;
        #pragma unroll
        for (int k = 0; k < 3; k++) {
            int idx2 = tid + k * 256;           // tap*64 + lane, 0..575
            if (idx2 < 576) {
                int tap  = idx2 >> 6;
                int lane = idx2 & 63;
                int r16  = lane & 15;
                int ibl  = (lane >> 4) * 8;
                short8 v;
                #pragma unroll
                for (int j = 0; j < 8; j++)
                    v[j] = (short)f2bf(tile[r16 * 288 + (ibl + j) * 9 + tap] * cs);
                *(short8*)(dst + ((size_t)tap * 32 * 64 + lane) * 8) = v;
            }
        }
    }
}

// ---------- K2: demod (blocks 0..1023) + pack_x (1024..3267)
// d[b][o] = rsqrt((1/4608) sum_i w2[o][i]*style[b][i]^2 + 1e-8)
// xsg[b8][ck16][khi4][hp66][wp66][j8], zero halo, i = ck*32+khi*8+j
__global__ void k2_demod_packx(const float* __restrict__ w2,
                               const float* __restrict__ style,
                               const float* __restrict__ x,
                               float* __restrict__ dvec,
                               ushort_t* __restrict__ xsg) {
    if (blockIdx.x < 1024) {
        int gw   = (blockIdx.x * 256 + threadIdx.x) >> 6;
        int lane = threadIdx.x & 63;
        int b = gw >> 9;
        int o = gw & 511;
        const float* w2p = w2 + (size_t)o * 512;
        const float* stp = style + b * 512;
        float acc = 0.f;
        #pragma unroll
        for (int i = 0; i < 512; i += 64) {
            float s = stp[i + lane];
            acc += w2p[i + lane] * s * s;
        }
        #pragma unroll
        for (int off = 32; off > 0; off >>= 1) acc += __shfl_down(acc, off, 64);
        if (lane == 0)
            dvec[b * 512 + o] = rsqrtf(acc * (1.0f / 4608.0f) + 1e-8f);
    } else {
        int t  = (blockIdx.x - 1024) * 256 + threadIdx.x;   // 0 .. 574463
        int g  = t % 17;
        int t2 = t / 17;
        int hp = t2 % 66;
        int t3 = t2 / 66;
        int khi = t3 & 3;
        int t4 = t3 >> 2;
        int ck = t4 & 15;
        int b  = t4 >> 4;
        size_t rowbase = (((size_t)(b * 16 + ck) * 4 + khi) * 66 + hp) * 66 * 8;
        if (g == 16) {   // wp = 0 and wp = 65 halo columns
            short8 z = (short8)0;
            *(short8*)(xsg + rowbase) = z;
            *(short8*)(xsg + rowbase + 65 * 8) = z;
            return;
        }
        int wp0 = 1 + g * 4;
        short8 v[4];
        if (hp >= 1 && hp <= 64) {
            #pragma unroll
            for (int j = 0; j < 8; j++) {
                int i = ck * 32 + khi * 8 + j;
                const float4 xv = *(const float4*)&x[(((size_t)b * 512 + i) * 64 + hp - 1) * 64 + wp0 - 1];
                const float s = style[b * 512 + i];
                v[0][j] = (short)f2bf(xv.x * s);
                v[1][j] = (short)f2bf(xv.y * s);
                v[2][j] = (short)f2bf(xv.z * s);
                v[3][j] = (short)f2bf(xv.w * s);
            }
        } else {
            #pragma unroll
            for (int p = 0; p < 4; p++)
                #pragma unroll
                for (int j = 0; j < 8; j++) v[p][j] = 0;
        }
        #pragma unroll
        for (int p = 0; p < 4; p++)
            *(short8*)(xsg + rowbase + (size_t)(wp0 + p) * 8) = v[p];
    }
}

// ---------- K3: conv (identical to R3). block M=128 (8 osub16), N=256 (4rx64c).
#define CKSTR  147456   // 9*32*64*8 ushorts
#define TAPSTR 16384    // 32*64*8
__global__ __launch_bounds__(256, 2) void conv_mfma_kernel(
        const ushort_t* __restrict__ xsg, const ushort_t* __restrict__ wpk,
        const float* __restrict__ dvec, float* __restrict__ out) {
    __shared__ ushort_t lds_x[2][4 * 6 * 66 * 8];   // 2 x 25344 B

    const int tid  = threadIdx.x;
    const int lane = tid & 63;
    const int wv   = tid >> 6;
    const int quad = lane >> 4;
    const int l16  = lane & 15;
    const int hq = blockIdx.x;
    const int b  = blockIdx.y;
    const int og = blockIdx.z;
    const int h0 = hq * 4;

    const int mbase = (wv & 1) * 4;
    const int nbase = (wv >> 1) * 8;

    floatx4 acc[4][8];
    #pragma unroll
    for (int i = 0; i < 4; i++)
        #pragma unroll
        for (int j = 0; j < 8; j++) acc[i][j] = (floatx4)(0.f);

    const size_t img_base = (size_t)b * 16 * (4 * 66 * 66 * 8) + h0 * (66 * 8);
    const int bl_base = quad * 3168 + l16 * 8;

    auto stage = [&](int ck, ushort_t* dst) {
        const ushort_t* src = xsg + img_base + (size_t)ck * (4 * 66 * 66 * 8);
        #pragma unroll
        for (int k = 0; k < 7; k++) {
            int off = tid * 16 + k * 4096;
            if (off < 25344) {
                int khi = off / 6336;
                int rem = off - khi * 6336;
                gload_lds16(src + (size_t)khi * (66 * 66 * 8) + (rem >> 1),
                            (char*)dst + off);
            }
        }
    };

    const ushort_t* wlane = wpk + (size_t)(og * 8 + mbase) * 512 + lane * 8;
    short8 a_cur[4], a_nxt[4];
    #pragma unroll
    for (int mi = 0; mi < 4; mi++) a_cur[mi] = *(const short8*)(wlane + mi * 512);

    stage(0, lds_x[0]);
    int buf = 0;

    for (int ck = 0; ck < 16; ck++) {
        __syncthreads();
        if (ck < 15) stage(ck + 1, lds_x[buf ^ 1]);
        const ushort_t* lp  = lds_x[buf];
        const ushort_t* wck = wlane + (size_t)ck * CKSTR;
        #pragma unroll
        for (int tap = 0; tap < 9; tap++) {
            const int dy = tap / 3, dx = tap % 3;
            const ushort_t* wnx = (tap < 8) ? (wck + (tap + 1) * TAPSTR)
                                            : (wck + (ck < 15 ? CKSTR : 0));
            #pragma unroll
            for (int mi = 0; mi < 4; mi++)
                a_nxt[mi] = *(const short8*)(wnx + mi * 512);
            #pragma unroll
            for (int q = 0; q < 8; q++) {
                const int nsub = nbase + q;
                const int off = bl_base + ((nsub >> 2) + dy) * 528 + ((nsub & 3) * 16 + dx) * 8;
                const short8 bfr = *(const short8*)&lp[off];
                #pragma unroll
                for (int mi = 0; mi < 4; mi++)
                    acc[mi][q] = __builtin_amdgcn_mfma_f32_16x16x32_bf16(
                        a_cur[mi], bfr, acc[mi][q], 0, 0, 0);
            }
            #pragma unroll
            for (int mi = 0; mi < 4; mi++) a_cur[mi] = a_nxt[mi];
        }
        buf ^= 1;
    }

    const float* dvb = dvec + b * COUT;
    #pragma unroll
    for (int mi = 0; mi < 4; mi++) {
        const int obase = (og * 8 + mbase + mi) * 16 + quad * 4;
        #pragma unroll
        for (int q = 0; q < 8; q++) {
            const int nsub = nbase + q;
            const int h = h0 + (nsub >> 2);
            const int col = (nsub & 3) * 16 + l16;
            #pragma unroll
            for (int r = 0; r < 4; r++) {
                const int o = obase + r;
                out[(((size_t)b * COUT + o) * 64 + h) * 64 + col] = acc[mi][q][r] * dvb[o];
            }
        }
    }
}

extern "C" void kernel_launch(void* const* d_in, const int* in_sizes, int n_in,
                              void* d_out, int out_size, void* d_ws, size_t ws_size,
                              hipStream_t stream) {
    const float* x  = (const float*)d_in[0];   // [8,512,64,64]
    const float* dl = (const float*)d_in[1];   // [8,512]
    const float* w  = (const float*)d_in[2];   // [512,512,3,3]
    const float* dw = (const float*)d_in[3];   // [512,512]
    const float* db = (const float*)d_in[4];   // [512]
    float* out = (float*)d_out;

    float* style = (float*)d_ws;                               // 4096 f32
    float* dvec  = style + 4096;                               // 4096 f32
    float* w2    = style + 8192;                               // 262144 f32
    ushort_t* wpk = (ushort_t*)((char*)d_ws + (2u << 20));     // 4.72 MB bf16
    ushort_t* xsg = (ushort_t*)((char*)d_ws + (8u << 20));     // 35.7 MB bf16

    k1_style_w2_packw<<<dim3(2560), dim3(256), 0, stream>>>(dl, dw, db, w, style, w2, wpk);
    k2_demod_packx  <<<dim3(3268), dim3(256), 0, stream>>>(w2, style, x, dvec, xsg);
    conv_mfma_kernel<<<dim3(16, 8, 4), dim3(256), 0, stream>>>(xsg, wpk, dvec, out);
}